// Round 6
// baseline (332.395 us; speedup 1.0000x reference)
//
#include <hip/hip_runtime.h>
#include <hip/hip_fp16.h>
#include <math.h>

// SPAIRPointFeatureNetwork on MI355X.
//   h_{p,j} = Q[j] - G[p];  celu monotonic => segmax(celu(h)) = celu(max_j Q[j] - G[p]).
//
// R10: 2x occupancy neutral. R11: cell-sort+translate neutral (layers faster,
//      infra ate it). Four neutral rounds and we have NEVER seen a layer
//      kernel's counters: the top-5 table is always the harness's 43us
//      poison-fills, so every kernel of ours is <43us and invisible.
// R12 (MEASUREMENT ROUND): identical to R11 except layer 3 runs its body
//      REP=8 times (idempotent; #pragma unroll 1 + asm memory clobber per rep
//      so gathers aren't CSE'd). This lifts L3 into the top-5 so we finally
//      read its true duration (delta/7 cross-check) and counters.
//      Decision rules pre-committed: VALUBusy<20% -> cache-path bound ->
//      sorted-neighbor transpose next; VALUBusy>40% -> addr/VALU;
//      L3_true<15us -> layers not the limiter -> kill sort, attack gaps.
// R13: R12 bench died to "MI355X container failed twice" (broker infra, not
//      the kernel). Resubmitting R12 unchanged.

#define NPTS 65536
#define KNBR 64
#define TILE 32
#define NCELL 4096

__device__ __forceinline__ float celu1(float x) {
    return x > 0.0f ? x : (__expf(x) - 1.0f);
}

__device__ __forceinline__ unsigned pkmax(unsigned a, unsigned b) {
    unsigned d;
    asm("v_pk_max_f16 %0, %1, %2" : "=v"(d) : "v"(a), "v"(b));
    return d;
}

__device__ __forceinline__ unsigned pack2(float a, float b) {
    __half2 h = __floats2half2_rn(a, b);
    return *(unsigned*)&h;
}

// ---- sort infra -----------------------------------------------------------

__global__ __launch_bounds__(256) void k_cell(
    const float* __restrict__ pos, float* __restrict__ dout, int out_size,
    int* __restrict__ cid, int* __restrict__ hist)
{
    int t = blockIdx.x * 256 + threadIdx.x;
    if (t < NPTS) {
        float p0 = pos[3 * t + 0];
        float p1 = pos[3 * t + 1];
        float p2 = pos[3 * t + 2];
        dout[3 * t + 0] = p0;
        dout[3 * t + 1] = p1;
        dout[3 * t + 2] = p2;
        int cx = min((int)(p0 * 16.0f), 15);
        int cy = min((int)(p1 * 16.0f), 15);
        int cz = min((int)(p2 * 16.0f), 15);
        int c = (cx * 16 + cy) * 16 + cz;
        cid[t] = c;
        atomicAdd(&hist[c], 1);
        for (int j = 35 * NPTS + t; j < out_size; j += NPTS)
            dout[j] = 0.0f;
    }
}

__global__ __launch_bounds__(64) void k_scan(
    const int* __restrict__ hist, int* __restrict__ cellptr)
{
    int l = threadIdx.x;
    int v[64];
    int s = 0;
#pragma unroll
    for (int i = 0; i < 64; ++i) { v[i] = s; s += hist[l * 64 + i]; }
    int run = s;
#pragma unroll
    for (int st = 1; st < 64; st <<= 1) {
        int o = __shfl_up(run, st, 64);
        if (l >= st) run += o;
    }
    int off = run - s;
#pragma unroll
    for (int i = 0; i < 64; ++i)
        cellptr[l * 64 + i] = off + v[i];
}

__global__ __launch_bounds__(256) void k_scatter(
    const float* __restrict__ pos, const int* __restrict__ cid,
    int* __restrict__ cellptr, unsigned short* __restrict__ perm,
    int* __restrict__ order, float* __restrict__ pos_s,
    const float* __restrict__ w1a, const float* __restrict__ b1a,
    __half* __restrict__ q1s)
{
    int t = blockIdx.x * 256 + threadIdx.x;
    if (t >= NPTS) return;
    int c = cid[t];
    int nid = atomicAdd(&cellptr[c], 1);
    perm[t] = (unsigned short)nid;
    order[nid] = t;
    float p0 = pos[3 * t + 0];
    float p1 = pos[3 * t + 1];
    float p2 = pos[3 * t + 2];
    pos_s[3 * nid + 0] = p0;
    pos_s[3 * nid + 1] = p1;
    pos_s[3 * nid + 2] = p2;
    float q[8];
#pragma unroll
    for (int ch = 0; ch < 8; ++ch) {
        float a = b1a[ch];
        a = fmaf(p0, w1a[0 * 8 + ch] + w1a[3 * 8 + ch], a);
        a = fmaf(p1, w1a[1 * 8 + ch] + w1a[4 * 8 + ch], a);
        a = fmaf(p2, w1a[2 * 8 + ch] + w1a[5 * 8 + ch], a);
        q[ch] = a;
    }
    uint4 pk;
    pk.x = pack2(q[0], q[1]);
    pk.y = pack2(q[2], q[3]);
    pk.z = pack2(q[4], q[5]);
    pk.w = pack2(q[6], q[7]);
    *(uint4*)(q1s + 8 * nid) = pk;
}

__global__ __launch_bounds__(256) void k_trans(
    const int* __restrict__ idx, const int* __restrict__ order,
    const unsigned short* __restrict__ perm, int* __restrict__ idxs)
{
    int g = blockIdx.x * 256 + threadIdx.x;
    int row = g >> 4;
    int j = g & 15;
    int old = order[row];
    int4 v = *(const int4*)(idx + old * KNBR + j * 4);
    int4 o;
    o.x = perm[v.x];
    o.y = perm[v.y];
    o.z = perm[v.z];
    o.w = perm[v.w];
    *(int4*)(idxs + row * KNBR + j * 4) = o;
}

// ---- fused layer (sorted space) ------------------------------------------
// REP: body repeated REP times (idempotent) purely for rocprof visibility.
template <int FH, int FOUT, int FHN, bool WRITEX, int REP>
__global__ __launch_bounds__(256, 8) void k_layer(
    const __half* __restrict__ q,
    const int* __restrict__ idx,
    const float* __restrict__ pos,
    const int* __restrict__ order,
    const float* __restrict__ wap,
    const float* __restrict__ wb,
    const float* __restrict__ bb,
    const float* __restrict__ wan,
    const float* __restrict__ ban,
    float* __restrict__ xout,
    __half* __restrict__ qnext)
{
    constexpr int SL  = FH / 8;
    constexpr int LPP = SL * 8;
    constexpr int PPW = 64 / LPP;
    constexpr int NIT = TILE / (4 * PPW);

    __shared__ uint4 m_lds[TILE * SL];

    int w  = threadIdx.x >> 6;
    int l  = threadIdx.x & 63;
    int pl = l / LPP;
    int u  = l % LPP;
    int c  = u % SL;
    int g  = u / SL;
    int tb = (blockIdx.x & 255) * (NPTS / TILE / 256) + (blockIdx.x >> 8);
    int pbase = tb * TILE;

#pragma unroll 1
    for (int rep = 0; rep < REP; ++rep) {
        asm volatile("" ::: "memory");   // defeat cross-rep CSE of gathers

#pragma unroll
        for (int it = 0; it < NIT; ++it) {
            int lp = it * (4 * PPW) + w * PPW + pl;
            int p  = pbase + lp;
            const uint4* ip = (const uint4*)(idx + p * KNBR + g * 8);
            uint4 i0 = ip[0];
            uint4 i1 = ip[1];
            uint4 v[8];
            v[0] = *(const uint4*)(q + (int)i0.x * FH + c * 8);
            v[1] = *(const uint4*)(q + (int)i0.y * FH + c * 8);
            v[2] = *(const uint4*)(q + (int)i0.z * FH + c * 8);
            v[3] = *(const uint4*)(q + (int)i0.w * FH + c * 8);
            v[4] = *(const uint4*)(q + (int)i1.x * FH + c * 8);
            v[5] = *(const uint4*)(q + (int)i1.y * FH + c * 8);
            v[6] = *(const uint4*)(q + (int)i1.z * FH + c * 8);
            v[7] = *(const uint4*)(q + (int)i1.w * FH + c * 8);

            unsigned ax = 0xFC00FC00u, ay = 0xFC00FC00u, az = 0xFC00FC00u, aw = 0xFC00FC00u;
#pragma unroll
            for (int k = 0; k < 8; ++k) {
                ax = pkmax(ax, v[k].x);
                ay = pkmax(ay, v[k].y);
                az = pkmax(az, v[k].z);
                aw = pkmax(aw, v[k].w);
            }
#pragma unroll
            for (int st = SL; st < LPP; st <<= 1) {
                ax = pkmax(ax, (unsigned)__shfl_xor((int)ax, st, 64));
                ay = pkmax(ay, (unsigned)__shfl_xor((int)ay, st, 64));
                az = pkmax(az, (unsigned)__shfl_xor((int)az, st, 64));
                aw = pkmax(aw, (unsigned)__shfl_xor((int)aw, st, 64));
            }
            if (g == 0) {
                uint4 r; r.x = ax; r.y = ay; r.z = az; r.w = aw;
                m_lds[lp * SL + c] = r;
            }
        }
        __syncthreads();

        if constexpr (WRITEX) {
            if (threadIdx.x < TILE * 4) {
                int pt  = threadIdx.x >> 2;
                int qtr = threadIdx.x & 3;
                int p   = pbase + pt;
                float p0 = pos[3 * p + 0];
                float p1 = pos[3 * p + 1];
                float p2 = pos[3 * p + 2];

                float h[FH];
#pragma unroll
                for (int s = 0; s < SL; ++s) {
                    uint4 vv = m_lds[pt * SL + s];
                    unsigned w4[4] = {vv.x, vv.y, vv.z, vv.w};
#pragma unroll
                    for (int k = 0; k < 4; ++k) {
                        float2 f = __half22float2(*(__half2*)&w4[k]);
                        h[s * 8 + k * 2 + 0] = f.x;
                        h[s * 8 + k * 2 + 1] = f.y;
                    }
                }
#pragma unroll
                for (int ch = 0; ch < FH; ++ch) {
                    float gg = p0 * wap[ch] + p1 * wap[FH + ch] + p2 * wap[2 * FH + ch];
                    h[ch] = celu1(h[ch] - gg);
                }
                float x[8];
#pragma unroll
                for (int j = 0; j < 8; ++j) {
                    int c2 = qtr * 8 + j;
                    float a = bb[c2];
#pragma unroll
                    for (int ch = 0; ch < FH; ++ch)
                        a = fmaf(h[ch], wb[ch * FOUT + c2], a);
                    x[j] = celu1(a);
                }
                int oldp = order[p];
                float4* xo = (float4*)(xout + (long long)oldp * FOUT + qtr * 8);
                xo[0] = make_float4(x[0], x[1], x[2], x[3]);
                xo[1] = make_float4(x[4], x[5], x[6], x[7]);
            }
        } else if (threadIdx.x < TILE) {
            int lt = threadIdx.x;
            int p  = pbase + lt;
            float p0 = pos[3 * p + 0];
            float p1 = pos[3 * p + 1];
            float p2 = pos[3 * p + 2];

            float h[FH];
#pragma unroll
            for (int s = 0; s < SL; ++s) {
                uint4 vv = m_lds[lt * SL + s];
                unsigned w4[4] = {vv.x, vv.y, vv.z, vv.w};
#pragma unroll
                for (int k = 0; k < 4; ++k) {
                    float2 f = __half22float2(*(__half2*)&w4[k]);
                    h[s * 8 + k * 2 + 0] = f.x;
                    h[s * 8 + k * 2 + 1] = f.y;
                }
            }
#pragma unroll
            for (int ch = 0; ch < FH; ++ch) {
                float gg = p0 * wap[ch] + p1 * wap[FH + ch] + p2 * wap[2 * FH + ch];
                h[ch] = celu1(h[ch] - gg);
            }
            float x[FOUT];
#pragma unroll
            for (int c2 = 0; c2 < FOUT; ++c2) {
                float a = bb[c2];
#pragma unroll
                for (int ch = 0; ch < FH; ++ch)
                    a = fmaf(h[ch], wb[ch * FOUT + c2], a);
                x[c2] = celu1(a);
            }
            if constexpr (FHN > 0) {
                uint4* qo = (uint4*)(qnext + p * FHN);
#pragma unroll
                for (int s = 0; s < FHN / 8; ++s) {
                    float qn[8];
#pragma unroll
                    for (int k = 0; k < 8; ++k) {
                        int cn = s * 8 + k;
                        float a = ban[cn];
#pragma unroll
                        for (int c2 = 0; c2 < FOUT; ++c2)
                            a = fmaf(x[c2], wan[c2 * FHN + cn], a);
                        a = fmaf(p0, wan[(FOUT + 0) * FHN + cn], a);
                        a = fmaf(p1, wan[(FOUT + 1) * FHN + cn], a);
                        a = fmaf(p2, wan[(FOUT + 2) * FHN + cn], a);
                        qn[k] = a;
                    }
                    uint4 pk;
                    pk.x = pack2(qn[0], qn[1]);
                    pk.y = pack2(qn[2], qn[3]);
                    pk.z = pack2(qn[4], qn[5]);
                    pk.w = pack2(qn[6], qn[7]);
                    qo[s] = pk;
                }
            }
        }
        __syncthreads();
    }
}

extern "C" void kernel_launch(void* const* d_in, const int* in_sizes, int n_in,
                              void* d_out, int out_size, void* d_ws, size_t ws_size,
                              hipStream_t stream) {
    const float* pos = (const float*)d_in[0];
    const int* idx = (const int*)d_in[4];
    const float* w1a = (const float*)d_in[5];
    const float* b1a = (const float*)d_in[6];
    const float* w1b = (const float*)d_in[7];
    const float* b1b = (const float*)d_in[8];
    const float* w2a = (const float*)d_in[9];
    const float* b2a = (const float*)d_in[10];
    const float* w2b = (const float*)d_in[11];
    const float* b2b = (const float*)d_in[12];
    const float* w3a = (const float*)d_in[13];
    const float* b3a = (const float*)d_in[14];
    const float* w3b = (const float*)d_in[15];
    const float* b3b = (const float*)d_in[16];
    float* out = (float*)d_out;

    char* ws = (char*)d_ws;
    __half* A      = (__half*)ws;
    __half* B      = (__half*)(ws + (4u << 20));
    int*    idxs   = (int*)(ws + (8u << 20));
    int*    cid    = (int*)(ws + (24u << 20));
    int*    order  = (int*)(ws + (25u << 20));
    unsigned short* perm = (unsigned short*)(ws + (26u << 20));
    int*    hist   = (int*)(ws + (27u << 20));
    int*    cellptr= (int*)(ws + (27u << 20) + (64u << 10));
    float*  pos_s  = (float*)(ws + (28u << 20));

    hipMemsetAsync(hist, 0, NCELL * sizeof(int), stream);
    k_cell<<<NPTS / 256, 256, 0, stream>>>(pos, out, out_size, cid, hist);
    k_scan<<<1, 64, 0, stream>>>(hist, cellptr);
    k_scatter<<<NPTS / 256, 256, 0, stream>>>(pos, cid, cellptr, perm, order,
                                              pos_s, w1a, b1a, A);
    k_trans<<<NPTS * 16 / 256, 256, 0, stream>>>(idx, order, perm, idxs);

    k_layer<8, 8, 16, false, 1><<<NPTS / TILE, 256, 0, stream>>>(
        A, idxs, pos_s, nullptr, w1a + 3 * 8, w1b, b1b, w2a, b2a, nullptr, B);
    k_layer<16, 16, 32, false, 1><<<NPTS / TILE, 256, 0, stream>>>(
        B, idxs, pos_s, nullptr, w2a + 8 * 16, w2b, b2b, w3a, b3a, nullptr, A);
    // MEASUREMENT: REP=8 on layer 3 only (idempotent) to surface it in top-5.
    k_layer<32, 32, 0, true, 8><<<NPTS / TILE, 256, 0, stream>>>(
        A, idxs, pos_s, order, w3a + 16 * 32, w3b, b3b, nullptr, nullptr,
        out + 3 * NPTS, nullptr);
}